// Round 8
// baseline (49.386 us; speedup 1.0000x reference)
//
#include <hip/hip_runtime.h>
#include <hip/hip_bf16.h>

#define B_   8
#define N_   16384
#define C_   64
#define M_   256
#define NPB  1048576   // N_*C_ per batch

typedef __attribute__((ext_vector_type(8))) short short8v;   // 8 bf16 = 4 VGPR
typedef __attribute__((ext_vector_type(16))) float f32x16;   // MFMA 32x32 acc
typedef __attribute__((ext_vector_type(4)))  float f32x4;    // MFMA 16x16 acc

union FragU { short8v s8; unsigned u[4]; };

__device__ inline unsigned pkbf(float a, float b) {
  union { __hip_bfloat162 h2; unsigned u; } cv;
  cv.h2 = __float22bfloat162_rn(make_float2(a, b));
  return cv.u;
}
__device__ inline unsigned short bfbits(float a) {
  union { __hip_bfloat16 h; unsigned short u; } cv;
  cv.h = __float2bfloat16(a);
  return cv.u;
}
__device__ inline float bf2f(unsigned short u) {
  union { unsigned u; float f; } cv;
  cv.u = ((unsigned)u) << 16;
  return cv.f;
}
__device__ inline short8v ld8(const unsigned short* p) {
  return *(const short8v*)p;
}

// v_permlane32_swap_b32: a'={a_lo|b_lo}, b'={a_hi|b_hi}
__device__ inline void plswap(unsigned &a, unsigned &b) {
#if __has_builtin(__builtin_amdgcn_permlane32_swap)
  typedef unsigned uint2v __attribute__((ext_vector_type(2)));
  uint2v r = __builtin_amdgcn_permlane32_swap(a, b, false, false);
  a = r[0]; b = r[1];
#else
  asm volatile("v_permlane32_swap_b32 %0, %1" : "+v"(a), "+v"(b));
#endif
}

// Repack 32x32 MFMA D-tile (row = (reg&3)+8*(reg>>2)+4*hi, col = lane&31) into
// two B-operand fragments (frag t elem j = k-row 16t+8hi+j, col = lane&31).
__device__ inline void repack16(const f32x16 s, FragU& f0, FragU& f1) {
  #pragma unroll
  for (int h = 0; h < 2; ++h) {
    FragU& f = h ? f1 : f0;
    unsigned a0 = pkbf(s[8*h+0], s[8*h+1]);
    unsigned a1 = pkbf(s[8*h+2], s[8*h+3]);
    unsigned a2 = pkbf(s[8*h+4], s[8*h+5]);
    unsigned a3 = pkbf(s[8*h+6], s[8*h+7]);
    plswap(a0, a2);
    plswap(a1, a3);
    f.u[0] = a0; f.u[1] = a1; f.u[2] = a2; f.u[3] = a3;
  }
}

// ---------------------------------------------------------------------------
// Prep:
//  blocks 0..1023  : kbt — conv B-frags, lane-ordered
//  blocks 1024..   : Wk' = (Wk @ Wq^T) * 0.125*log2e ; Wv' = Wv @ Wp   (fp32)
// ---------------------------------------------------------------------------
__global__ __launch_bounds__(256) void prep(const float* __restrict__ Wq,
                                            const float* __restrict__ Wp,
                                            const float* __restrict__ Kw,
                                            const float* __restrict__ Wkv,
                                            unsigned short* __restrict__ kbt,
                                            float* __restrict__ wkp,
                                            float* __restrict__ wvp) {
  const int gi = blockIdx.x;
  if (gi < 1024) {
    const int idx = gi * 256 + threadIdx.x;      // 0..262143
    const int j = idx & 7, l = (idx >> 3) & 63, s = (idx >> 9) & 15;
    const int w = (idx >> 13) & 3, kw = idx >> 15;
    const int e = s * 32 + 8 * (l >> 4) + j;
    const int par = e >> 8, ci = (e >> 2) & 63, jj = e & 3;
    const int kh = 2 * jj + par, co = 16 * w + (l & 15);
    kbt[idx] = bfbits(Kw[(size_t)((kh * 8 + kw) * 64 + ci) * 64 + co]);
  } else {
    const int idx = (gi - 1024) * 256 + threadIdx.x;  // 0..8191
    const int c = idx & 63, cc = (idx >> 6) & 63, sel = idx >> 12;
    float s = 0.f;
    if (sel == 0) {
      #pragma unroll 8
      for (int d = 0; d < 64; ++d) s += Wkv[cc * 128 + d] * Wq[c * 64 + d];
      wkp[cc * 64 + c] = s * 0.125f * 1.4426950408889634f;  // fold scale + log2e
    } else {
      #pragma unroll 8
      for (int d = 0; d < 64; ++d) s += Wkv[cc * 128 + 64 + d] * Wp[d * 64 + c];
      wvp[cc * 64 + c] = s;
    }
  }
}

// ---------------------------------------------------------------------------
// Conv as MFMA GEMM, no LDS (R4/R5 proven version).
// ---------------------------------------------------------------------------
__global__ __launch_bounds__(256) void conv_mfma(const float* __restrict__ x,
                                                 const unsigned short* __restrict__ kbt,
                                                 unsigned short* __restrict__ xrb) {
  const int kw = blockIdx.x & 7;
  const int ow = (blockIdx.x >> 3) & 15;
  const int b  = blockIdx.x >> 7;
  const int t  = threadIdx.x, w = t >> 6, l = t & 63;
  const int oh = l & 15, kg = l >> 4;

  const float* xb = x + (size_t)b * NPB + (size_t)((ow * 8 + kw) * 64) * 64 + oh * 4;
  const unsigned short* kb = kbt + (size_t)(((kw * 4 + w) * 16) * 64 + l) * 8;

  f32x4 acc = {0.f, 0.f, 0.f, 0.f};
  #pragma unroll
  for (int s = 0; s < 16; ++s) {
    const int par = (s >= 8) ? 1 : 0;
    const int ci  = ((s * 8) + kg * 2) & 63;
    const float* ax = xb + (size_t)par * 524288 + ci * 64;
    const float4 a0 = *(const float4*)(ax);
    const float4 a1 = *(const float4*)(ax + 64);
    FragU af;
    af.u[0] = pkbf(a0.x, a0.y); af.u[1] = pkbf(a0.z, a0.w);
    af.u[2] = pkbf(a1.x, a1.y); af.u[3] = pkbf(a1.z, a1.w);
    const short8v bfrag = ld8(kb + s * 512);
    acc = __builtin_amdgcn_mfma_f32_16x16x32_bf16(af.s8, bfrag, acc, 0, 0, 0);
  }
  unsigned short* dst = xrb + (size_t)kw * 131072
                      + ((size_t)b * 256 + ow) * 64 + w * 16 + (l & 15);
  #pragma unroll
  for (int r = 0; r < 4; ++r)
    dst[(size_t)((l >> 4) * 4 + r) * 1024] = bfbits(acc[r]);
}

// ---------------------------------------------------------------------------
// Reduce split-K + bias, LayerNorm, folded weights K' / V', frag-ordered out.
// ---------------------------------------------------------------------------
__global__ __launch_bounds__(256) void ln_kv(const unsigned short* __restrict__ xrb,
                                             const float* __restrict__ sr_bias,
                                             const float* __restrict__ gamma,
                                             const float* __restrict__ beta,
                                             const float* __restrict__ wkp,
                                             const float* __restrict__ wvp,
                                             unsigned short* __restrict__ kbl,
                                             unsigned short* __restrict__ vbl) {
  const int w   = threadIdx.x >> 6;
  const int row = blockIdx.x * 4 + w;   // 0..2047  (= b*256 + m)
  const int c   = threadIdx.x & 63;
  float val = sr_bias[c];
  #pragma unroll
  for (int s = 0; s < 8; ++s)
    val += bf2f(xrb[(size_t)s * 131072 + (size_t)row * 64 + c]);

  float sum = val;
  #pragma unroll
  for (int off = 32; off; off >>= 1) sum += __shfl_xor(sum, off, 64);
  const float mu = sum * (1.f / 64.f);
  const float d  = val - mu;
  float vs = d * d;
  #pragma unroll
  for (int off = 32; off; off >>= 1) vs += __shfl_xor(vs, off, 64);
  const float rs = rsqrtf(vs * (1.f / 64.f) + 1e-3f);
  const float ln = d * rs * gamma[c] + beta[c];

  __shared__ float lnrow[4][64];
  lnrow[w][c] = ln;
  __syncthreads();

  float ka = 0.f, va = 0.f;
  #pragma unroll 8
  for (int cc = 0; cc < 64; ++cc) {
    const float l = lnrow[w][cc];
    ka += l * wkp[cc * 64 + c];
    va += l * wvp[cc * 64 + c];
  }
  const int m = row & 255, bb = row >> 8;
  // K-frag: value(tt,l,j) = K'[kt*32 + (l&31)][16tt + 8*(l>>5) + j]
  kbl[(size_t)bb * 16384
      + (size_t)((((m >> 5) * 4 + (c >> 4)) * 64) + (m & 31) + 32 * ((c >> 3) & 1)) * 8
      + (c & 7)] = bfbits(ka);
  // V-frag: value(ot,kt,f,l,j) = V'[kt*32 + f*16 + 8*(l>>5) + j][32*ot + (l&31)]
  vbl[(size_t)bb * 16384
      + (size_t)(((c >> 5) * 8 + (m >> 5)) * 2 + ((m >> 4) & 1)) * 512
      + (size_t)((c & 31) + 32 * ((m >> 3) & 1)) * 8
      + (m & 7)] = bfbits(va);
}

// ---------------------------------------------------------------------------
// Fused attention: 64 query rows per wave (two column-tiles A/B sharing the
// K-fragments).  S = K'·X^T ; P = exp2(S) ; F^T = V'^T P^T ; out = F/ss + bp.
// Per kt: 8 ld8 + 16 MFMA.  512 blocks x 4 waves; 256 rows per block.
// ---------------------------------------------------------------------------
__global__ __launch_bounds__(256, 2) void attn_mfma(const float* __restrict__ x,
                                                    const unsigned short* __restrict__ kbl,
                                                    const unsigned short* __restrict__ vbl,
                                                    const float* __restrict__ bp,
                                                    float* __restrict__ out) {
  __shared__ float ot[128 * 68];
  const int t    = threadIdx.x;
  const int w    = t >> 6;
  const int l    = t & 63;
  const int l31  = l & 31;
  const int hi   = l >> 5;
  const int b    = blockIdx.x >> 6;
  const int tile = blockIdx.x & 63;
  const size_t nrow = (size_t)b * N_ + (size_t)tile * 256;
  const int qA = w * 64 + l31;         // first query row of this lane
  // (second tile = qA + 32)

  // ---- X^T B-fragments for both column tiles ----
  const float* xrowA = x + (nrow + qA) * 64;
  FragU xa[4], xbb[4];
  #pragma unroll
  for (int tt = 0; tt < 4; ++tt) {
    const float* pA = xrowA + 16 * tt + 8 * hi;
    const float4 a0 = *(const float4*)(pA);
    const float4 a1 = *(const float4*)(pA + 4);
    xa[tt].u[0] = pkbf(a0.x, a0.y); xa[tt].u[1] = pkbf(a0.z, a0.w);
    xa[tt].u[2] = pkbf(a1.x, a1.y); xa[tt].u[3] = pkbf(a1.z, a1.w);
    const float* pB = pA + 32 * 64;
    const float4 b0 = *(const float4*)(pB);
    const float4 b1 = *(const float4*)(pB + 4);
    xbb[tt].u[0] = pkbf(b0.x, b0.y); xbb[tt].u[1] = pkbf(b0.z, b0.w);
    xbb[tt].u[2] = pkbf(b1.x, b1.y); xbb[tt].u[3] = pkbf(b1.z, b1.w);
  }

  // ---- main attention loop over 8 key tiles of 32 ----
  const unsigned short* kfp = kbl + (size_t)b * 16384 + l * 8;
  const unsigned short* vfp = vbl + (size_t)b * 16384 + l * 8;
  f32x16 Z;
  #pragma unroll
  for (int r = 0; r < 16; ++r) Z[r] = 0.f;
  f32x16 OA0 = Z, OA1 = Z, OB0 = Z, OB1 = Z;
  float ssA = 0.f, ssB = 0.f;

  #pragma unroll
  for (int kt = 0; kt < 8; ++kt) {
    const short8v vf00 = ld8(vfp + (size_t)((kt * 2 + 0) * 512));
    const short8v vf01 = ld8(vfp + (size_t)((kt * 2 + 1) * 512));
    const short8v vf10 = ld8(vfp + (size_t)(((8 + kt) * 2 + 0) * 512));
    const short8v vf11 = ld8(vfp + (size_t)(((8 + kt) * 2 + 1) * 512));
    const short8v ak0 = ld8(kfp + (size_t)((kt * 4 + 0) * 512));
    const short8v ak1 = ld8(kfp + (size_t)((kt * 4 + 1) * 512));
    const short8v ak2 = ld8(kfp + (size_t)((kt * 4 + 2) * 512));
    const short8v ak3 = ld8(kfp + (size_t)((kt * 4 + 3) * 512));
    // two independent S chains (ILP)
    f32x16 Sa = __builtin_amdgcn_mfma_f32_32x32x16_bf16(ak0, xa[0].s8, Z, 0, 0, 0);
    f32x16 Sb = __builtin_amdgcn_mfma_f32_32x32x16_bf16(ak0, xbb[0].s8, Z, 0, 0, 0);
    Sa = __builtin_amdgcn_mfma_f32_32x32x16_bf16(ak1, xa[1].s8, Sa, 0, 0, 0);
    Sb = __builtin_amdgcn_mfma_f32_32x32x16_bf16(ak1, xbb[1].s8, Sb, 0, 0, 0);
    Sa = __builtin_amdgcn_mfma_f32_32x32x16_bf16(ak2, xa[2].s8, Sa, 0, 0, 0);
    Sb = __builtin_amdgcn_mfma_f32_32x32x16_bf16(ak2, xbb[2].s8, Sb, 0, 0, 0);
    Sa = __builtin_amdgcn_mfma_f32_32x32x16_bf16(ak3, xa[3].s8, Sa, 0, 0, 0);
    Sb = __builtin_amdgcn_mfma_f32_32x32x16_bf16(ak3, xbb[3].s8, Sb, 0, 0, 0);
    f32x16 Pa, Pb;
    #pragma unroll
    for (int r = 0; r < 16; ++r) {
      const float pa = exp2f(Sa[r]);  Pa[r] = pa; ssA += pa;
      const float pb = exp2f(Sb[r]);  Pb[r] = pb; ssB += pb;
    }
    FragU fa0, fa1, fb0, fb1;
    repack16(Pa, fa0, fa1);
    repack16(Pb, fb0, fb1);
    OA0 = __builtin_amdgcn_mfma_f32_32x32x16_bf16(vf00, fa0.s8, OA0, 0, 0, 0);
    OB0 = __builtin_amdgcn_mfma_f32_32x32x16_bf16(vf00, fb0.s8, OB0, 0, 0, 0);
    OA1 = __builtin_amdgcn_mfma_f32_32x32x16_bf16(vf10, fa0.s8, OA1, 0, 0, 0);
    OB1 = __builtin_amdgcn_mfma_f32_32x32x16_bf16(vf10, fb0.s8, OB1, 0, 0, 0);
    OA0 = __builtin_amdgcn_mfma_f32_32x32x16_bf16(vf01, fa1.s8, OA0, 0, 0, 0);
    OB0 = __builtin_amdgcn_mfma_f32_32x32x16_bf16(vf01, fb1.s8, OB0, 0, 0, 0);
    OA1 = __builtin_amdgcn_mfma_f32_32x32x16_bf16(vf11, fa1.s8, OA1, 0, 0, 0);
    OB1 = __builtin_amdgcn_mfma_f32_32x32x16_bf16(vf11, fb1.s8, OB1, 0, 0, 0);
  }

  // ---- epilogue in two phases reusing the 34 KB transpose buffer ----
  ssA += __shfl_xor(ssA, 32);
  ssB += __shfl_xor(ssB, 32);
  const float invA = 1.f / ssA, invB = 1.f / ssB;
  const int slot = w * 32 + l31;

  #pragma unroll
  for (int g = 0; g < 4; ++g) {
    const int co0 = 8 * g + 4 * hi, co1 = 32 + 8 * g + 4 * hi;
    const float4 b0 = *(const float4*)(bp + co0);
    const float4 b1 = *(const float4*)(bp + co1);
    *(float4*)&ot[slot * 68 + co0] =
        make_float4(OA0[4*g+0]*invA + b0.x, OA0[4*g+1]*invA + b0.y,
                    OA0[4*g+2]*invA + b0.z, OA0[4*g+3]*invA + b0.w);
    *(float4*)&ot[slot * 68 + co1] =
        make_float4(OA1[4*g+0]*invA + b1.x, OA1[4*g+1]*invA + b1.y,
                    OA1[4*g+2]*invA + b1.z, OA1[4*g+3]*invA + b1.w);
  }
  __syncthreads();
  {
    #pragma unroll
    for (int i = 0; i < 8; ++i) {
      const int idx = i * 256 + t;
      const int s = idx >> 4, c4 = idx & 15;
      const int wp = s >> 5, r = s & 31;
      *(float4*)(out + (nrow + wp * 64 + r) * 64 + c4 * 4) =
          *(const float4*)&ot[s * 68 + c4 * 4];
    }
  }
  __syncthreads();
  #pragma unroll
  for (int g = 0; g < 4; ++g) {
    const int co0 = 8 * g + 4 * hi, co1 = 32 + 8 * g + 4 * hi;
    const float4 b0 = *(const float4*)(bp + co0);
    const float4 b1 = *(const float4*)(bp + co1);
    *(float4*)&ot[slot * 68 + co0] =
        make_float4(OB0[4*g+0]*invB + b0.x, OB0[4*g+1]*invB + b0.y,
                    OB0[4*g+2]*invB + b0.z, OB0[4*g+3]*invB + b0.w);
    *(float4*)&ot[slot * 68 + co1] =
        make_float4(OB1[4*g+0]*invB + b1.x, OB1[4*g+1]*invB + b1.y,
                    OB1[4*g+2]*invB + b1.z, OB1[4*g+3]*invB + b1.w);
  }
  __syncthreads();
  {
    #pragma unroll
    for (int i = 0; i < 8; ++i) {
      const int idx = i * 256 + t;
      const int s = idx >> 4, c4 = idx & 15;
      const int wp = s >> 5, r = s & 31;
      *(float4*)(out + (nrow + wp * 64 + 32 + r) * 64 + c4 * 4) =
          *(const float4*)&ot[s * 68 + c4 * 4];
    }
  }
}

// ---------------------------------------------------------------------------
extern "C" void kernel_launch(void* const* d_in, const int* in_sizes, int n_in,
                              void* d_out, int out_size, void* d_ws, size_t ws_size,
                              hipStream_t stream) {
  const float* x   = (const float*)d_in[0];
  const float* Wq  = (const float*)d_in[3];
  const float* Wkv = (const float*)d_in[4];
  const float* Kw  = (const float*)d_in[5];
  const float* sb  = (const float*)d_in[6];
  const float* gam = (const float*)d_in[7];
  const float* bet = (const float*)d_in[8];
  const float* Wp  = (const float*)d_in[9];
  const float* bp  = (const float*)d_in[10];
  float* out = (float*)d_out;

  unsigned short* xrb = (unsigned short*)d_ws;        // 8*131072 = 2 MB
  unsigned short* kbl = xrb + 1048576;                // 256 KB
  unsigned short* vbl = kbl + 131072;                 // 256 KB
  unsigned short* kbt = vbl + 131072;                 // 512 KB
  float* wkp = (float*)(kbt + 262144);                // 16 KB
  float* wvp = wkp + 4096;                            // 16 KB

  prep<<<1056, 256, 0, stream>>>(Wq, Wp, Kw, Wkv, kbt, wkp, wvp);
  conv_mfma<<<1024, 256, 0, stream>>>(x, kbt, xrb);
  ln_kv<<<512, 256, 0, stream>>>(xrb, sb, gam, bet, wkp, wvp, kbl, vbl);
  attn_mfma<<<512, 256, 0, stream>>>(x, kbl, vbl, bp, out);
}

// Round 10
// 47.858 us; speedup vs baseline: 1.0319x; 1.0319x over previous
//
#include <hip/hip_runtime.h>
#include <hip/hip_bf16.h>

#define B_   8
#define N_   16384
#define C_   64
#define M_   256
#define NPB  1048576   // N_*C_ per batch

typedef __attribute__((ext_vector_type(8))) short short8v;   // 8 bf16 = 4 VGPR
typedef __attribute__((ext_vector_type(16))) float f32x16;   // MFMA 32x32 acc
typedef __attribute__((ext_vector_type(4)))  float f32x4;    // MFMA 16x16 acc

union FragU { short8v s8; unsigned u[4]; };

__device__ inline unsigned pkbf(float a, float b) {
  union { __hip_bfloat162 h2; unsigned u; } cv;
  cv.h2 = __float22bfloat162_rn(make_float2(a, b));
  return cv.u;
}
__device__ inline unsigned short bfbits(float a) {
  union { __hip_bfloat16 h; unsigned short u; } cv;
  cv.h = __float2bfloat16(a);
  return cv.u;
}
__device__ inline float bf2f(unsigned short u) {
  union { unsigned u; float f; } cv;
  cv.u = ((unsigned)u) << 16;
  return cv.f;
}
__device__ inline short8v ld8(const unsigned short* p) {
  return *(const short8v*)p;
}

// v_permlane32_swap_b32: a'={a_lo|b_lo}, b'={a_hi|b_hi}
__device__ inline void plswap(unsigned &a, unsigned &b) {
#if __has_builtin(__builtin_amdgcn_permlane32_swap)
  typedef unsigned uint2v __attribute__((ext_vector_type(2)));
  uint2v r = __builtin_amdgcn_permlane32_swap(a, b, false, false);
  a = r[0]; b = r[1];
#else
  asm volatile("v_permlane32_swap_b32 %0, %1" : "+v"(a), "+v"(b));
#endif
}

// Repack 32x32 MFMA D-tile (row = (reg&3)+8*(reg>>2)+4*hi, col = lane&31) into
// two B-operand fragments (frag t elem j = k-row 16t+8hi+j, col = lane&31).
__device__ inline void repack16(const f32x16 s, FragU& f0, FragU& f1) {
  #pragma unroll
  for (int h = 0; h < 2; ++h) {
    FragU& f = h ? f1 : f0;
    unsigned a0 = pkbf(s[8*h+0], s[8*h+1]);
    unsigned a1 = pkbf(s[8*h+2], s[8*h+3]);
    unsigned a2 = pkbf(s[8*h+4], s[8*h+5]);
    unsigned a3 = pkbf(s[8*h+6], s[8*h+7]);
    plswap(a0, a2);
    plswap(a1, a3);
    f.u[0] = a0; f.u[1] = a1; f.u[2] = a2; f.u[3] = a3;
  }
}

// ---------------------------------------------------------------------------
// Prep:
//  blocks 0..1023  : kbt — conv B-frags, lane-ordered
//  blocks 1024..   : Wk' = (Wk @ Wq^T) * 0.125*log2e ; Wv' = Wv @ Wp   (fp32)
// ---------------------------------------------------------------------------
__global__ __launch_bounds__(256) void prep(const float* __restrict__ Wq,
                                            const float* __restrict__ Wp,
                                            const float* __restrict__ Kw,
                                            const float* __restrict__ Wkv,
                                            unsigned short* __restrict__ kbt,
                                            float* __restrict__ wkp,
                                            float* __restrict__ wvp) {
  const int gi = blockIdx.x;
  if (gi < 1024) {
    const int idx = gi * 256 + threadIdx.x;      // 0..262143
    const int j = idx & 7, l = (idx >> 3) & 63, s = (idx >> 9) & 15;
    const int w = (idx >> 13) & 3, kw = idx >> 15;
    const int e = s * 32 + 8 * (l >> 4) + j;
    const int par = e >> 8, ci = (e >> 2) & 63, jj = e & 3;
    const int kh = 2 * jj + par, co = 16 * w + (l & 15);
    kbt[idx] = bfbits(Kw[(size_t)((kh * 8 + kw) * 64 + ci) * 64 + co]);
  } else {
    const int idx = (gi - 1024) * 256 + threadIdx.x;  // 0..8191
    const int c = idx & 63, cc = (idx >> 6) & 63, sel = idx >> 12;
    float s = 0.f;
    if (sel == 0) {
      #pragma unroll 8
      for (int d = 0; d < 64; ++d) s += Wkv[cc * 128 + d] * Wq[c * 64 + d];
      wkp[cc * 64 + c] = s * 0.125f * 1.4426950408889634f;  // fold scale + log2e
    } else {
      #pragma unroll 8
      for (int d = 0; d < 64; ++d) s += Wkv[cc * 128 + 64 + d] * Wp[d * 64 + c];
      wvp[cc * 64 + c] = s;
    }
  }
}

// ---------------------------------------------------------------------------
// Conv as MFMA GEMM, no LDS (R4/R5 proven version).
// ---------------------------------------------------------------------------
__global__ __launch_bounds__(256) void conv_mfma(const float* __restrict__ x,
                                                 const unsigned short* __restrict__ kbt,
                                                 unsigned short* __restrict__ xrb) {
  const int kw = blockIdx.x & 7;
  const int ow = (blockIdx.x >> 3) & 15;
  const int b  = blockIdx.x >> 7;
  const int t  = threadIdx.x, w = t >> 6, l = t & 63;
  const int oh = l & 15, kg = l >> 4;

  const float* xb = x + (size_t)b * NPB + (size_t)((ow * 8 + kw) * 64) * 64 + oh * 4;
  const unsigned short* kb = kbt + (size_t)(((kw * 4 + w) * 16) * 64 + l) * 8;

  f32x4 acc = {0.f, 0.f, 0.f, 0.f};
  #pragma unroll
  for (int s = 0; s < 16; ++s) {
    const int par = (s >= 8) ? 1 : 0;
    const int ci  = ((s * 8) + kg * 2) & 63;
    const float* ax = xb + (size_t)par * 524288 + ci * 64;
    const float4 a0 = *(const float4*)(ax);
    const float4 a1 = *(const float4*)(ax + 64);
    FragU af;
    af.u[0] = pkbf(a0.x, a0.y); af.u[1] = pkbf(a0.z, a0.w);
    af.u[2] = pkbf(a1.x, a1.y); af.u[3] = pkbf(a1.z, a1.w);
    const short8v bfrag = ld8(kb + s * 512);
    acc = __builtin_amdgcn_mfma_f32_16x16x32_bf16(af.s8, bfrag, acc, 0, 0, 0);
  }
  unsigned short* dst = xrb + (size_t)kw * 131072
                      + ((size_t)b * 256 + ow) * 64 + w * 16 + (l & 15);
  #pragma unroll
  for (int r = 0; r < 4; ++r)
    dst[(size_t)((l >> 4) * 4 + r) * 1024] = bfbits(acc[r]);
}

// ---------------------------------------------------------------------------
// Reduce split-K + bias, LayerNorm, folded weights K' / V', frag-ordered out.
// ---------------------------------------------------------------------------
__global__ __launch_bounds__(256) void ln_kv(const unsigned short* __restrict__ xrb,
                                             const float* __restrict__ sr_bias,
                                             const float* __restrict__ gamma,
                                             const float* __restrict__ beta,
                                             const float* __restrict__ wkp,
                                             const float* __restrict__ wvp,
                                             unsigned short* __restrict__ kbl,
                                             unsigned short* __restrict__ vbl) {
  const int w   = threadIdx.x >> 6;
  const int row = blockIdx.x * 4 + w;   // 0..2047  (= b*256 + m)
  const int c   = threadIdx.x & 63;
  float val = sr_bias[c];
  #pragma unroll
  for (int s = 0; s < 8; ++s)
    val += bf2f(xrb[(size_t)s * 131072 + (size_t)row * 64 + c]);

  float sum = val;
  #pragma unroll
  for (int off = 32; off; off >>= 1) sum += __shfl_xor(sum, off, 64);
  const float mu = sum * (1.f / 64.f);
  const float d  = val - mu;
  float vs = d * d;
  #pragma unroll
  for (int off = 32; off; off >>= 1) vs += __shfl_xor(vs, off, 64);
  const float rs = rsqrtf(vs * (1.f / 64.f) + 1e-3f);
  const float ln = d * rs * gamma[c] + beta[c];

  __shared__ float lnrow[4][64];
  lnrow[w][c] = ln;
  __syncthreads();

  float ka = 0.f, va = 0.f;
  #pragma unroll 8
  for (int cc = 0; cc < 64; ++cc) {
    const float l = lnrow[w][cc];
    ka += l * wkp[cc * 64 + c];
    va += l * wvp[cc * 64 + c];
  }
  const int m = row & 255, bb = row >> 8;
  // K-frag: value(tt,l,j) = K'[kt*32 + (l&31)][16tt + 8*(l>>5) + j]
  kbl[(size_t)bb * 16384
      + (size_t)((((m >> 5) * 4 + (c >> 4)) * 64) + (m & 31) + 32 * ((c >> 3) & 1)) * 8
      + (c & 7)] = bfbits(ka);
  // V-frag: value(ot,kt,f,l,j) = V'[kt*32 + f*16 + 8*(l>>5) + j][32*ot + (l&31)]
  vbl[(size_t)bb * 16384
      + (size_t)(((c >> 5) * 8 + (m >> 5)) * 2 + ((m >> 4) & 1)) * 512
      + (size_t)((c & 31) + 32 * ((m >> 3) & 1)) * 8
      + (m & 7)] = bfbits(va);
}

// ---------------------------------------------------------------------------
// Fused attention: one block = 8 waves = 256 q-rows of one batch; the batch's
// entire K'/V' (64 KB) is staged once in LDS, shared by all waves.  Frag reads
// become conflict-free ds_read_b128.  S = K'·X^T ; P = exp2(S) ;
// F^T = V'^T P^T ; out = F/ss + bp.  Epilogue: two-phase LDS transpose
// reusing the K/V space.  512 blocks x 512 threads; 2 blocks/CU (64 KB LDS).
// ---------------------------------------------------------------------------
__global__ __launch_bounds__(512, 4) void attn_mfma(const float* __restrict__ x,
                                                    const unsigned short* __restrict__ kbl,
                                                    const unsigned short* __restrict__ vbl,
                                                    const float* __restrict__ bp,
                                                    float* __restrict__ out) {
  __shared__ char smem[65536];
  unsigned short* ks = (unsigned short*)smem;          // 16384 ushorts (32 KB)
  unsigned short* vs = ks + 16384;                     // 16384 ushorts (32 KB)
  const int t    = threadIdx.x;
  const int w    = t >> 6;
  const int l    = t & 63;
  const int l31  = l & 31;
  const int hi   = l >> 5;
  const int b    = blockIdx.x >> 6;
  const int tile = blockIdx.x & 63;
  const size_t nrow = (size_t)b * N_ + (size_t)tile * 256;
  const int qloc = w * 32 + l31;     // local q-row 0..255

  // ---- stage K'/V' for this batch: coalesced 16B copies ----
  {
    typedef __attribute__((ext_vector_type(2))) unsigned long long ull2;
    const ull2* kg = (const ull2*)(kbl + (size_t)b * 16384);
    const ull2* vg = (const ull2*)(vbl + (size_t)b * 16384);
    ull2* kd = (ull2*)ks;
    ull2* vd = (ull2*)vs;
    #pragma unroll
    for (int i = 0; i < 4; ++i) {
      kd[i * 512 + t] = kg[i * 512 + t];
      vd[i * 512 + t] = vg[i * 512 + t];
    }
  }

  // ---- X^T B-fragments: own query row, fp32 -> bf16 (overlaps staging) ----
  const float* xrow = x + (nrow + qloc) * 64;
  FragU xb[4];
  #pragma unroll
  for (int tt = 0; tt < 4; ++tt) {
    const float* p = xrow + 16 * tt + 8 * hi;
    const float4 x0 = *(const float4*)(p);
    const float4 x1 = *(const float4*)(p + 4);
    xb[tt].u[0] = pkbf(x0.x, x0.y); xb[tt].u[1] = pkbf(x0.z, x0.w);
    xb[tt].u[2] = pkbf(x1.x, x1.y); xb[tt].u[3] = pkbf(x1.z, x1.w);
  }
  __syncthreads();

  // ---- main attention loop over 8 key tiles of 32 (frags from LDS) ----
  const unsigned short* kfp = ks + l * 8;
  const unsigned short* vfp = vs + l * 8;
  f32x16 Z;
  #pragma unroll
  for (int r = 0; r < 16; ++r) Z[r] = 0.f;
  f32x16 O0 = Z, O1 = Z;
  float ss = 0.f;

  #pragma unroll
  for (int kt = 0; kt < 8; ++kt) {
    const short8v vf00 = ld8(vfp + (size_t)((kt * 2 + 0) * 512));
    const short8v vf01 = ld8(vfp + (size_t)((kt * 2 + 1) * 512));
    const short8v vf10 = ld8(vfp + (size_t)(((8 + kt) * 2 + 0) * 512));
    const short8v vf11 = ld8(vfp + (size_t)(((8 + kt) * 2 + 1) * 512));
    f32x16 S = __builtin_amdgcn_mfma_f32_32x32x16_bf16(
        ld8(kfp + (size_t)((kt * 4 + 0) * 512)), xb[0].s8, Z, 0, 0, 0);
    #pragma unroll
    for (int tt = 1; tt < 4; ++tt) {
      const short8v ak = ld8(kfp + (size_t)((kt * 4 + tt) * 512));
      S = __builtin_amdgcn_mfma_f32_32x32x16_bf16(ak, xb[tt].s8, S, 0, 0, 0);
    }
    f32x16 P;
    #pragma unroll
    for (int r = 0; r < 16; ++r) {
      const float pv = exp2f(S[r]);   // scale+log2e folded into K'
      P[r] = pv; ss += pv;
    }
    FragU f0, f1;
    repack16(P, f0, f1);
    O0 = __builtin_amdgcn_mfma_f32_32x32x16_bf16(vf00, f0.s8, O0, 0, 0, 0);
    O0 = __builtin_amdgcn_mfma_f32_32x32x16_bf16(vf01, f1.s8, O0, 0, 0, 0);
    O1 = __builtin_amdgcn_mfma_f32_32x32x16_bf16(vf10, f0.s8, O1, 0, 0, 0);
    O1 = __builtin_amdgcn_mfma_f32_32x32x16_bf16(vf11, f1.s8, O1, 0, 0, 0);
  }

  // ---- normalize ----
  ss += __shfl_xor(ss, 32);
  const float inv = 1.f / ss;

  // ---- epilogue: two-phase LDS transpose reusing smem (K/V dead now) ----
  float* ot = (float*)smem;          // [128][68] = 34.8 KB
  __syncthreads();                   // all waves done reading ks/vs

  #pragma unroll
  for (int ph = 0; ph < 2; ++ph) {
    if ((w >> 2) == ph) {            // waves 0-3 in phase 0, 4-7 in phase 1
      const int slot = (w & 3) * 32 + l31;
      #pragma unroll
      for (int g = 0; g < 4; ++g) {
        const int co0 = 8 * g + 4 * hi, co1 = 32 + 8 * g + 4 * hi;
        const float4 b0 = *(const float4*)(bp + co0);
        const float4 b1 = *(const float4*)(bp + co1);
        *(float4*)&ot[slot * 68 + co0] =
            make_float4(O0[4*g+0]*inv + b0.x, O0[4*g+1]*inv + b0.y,
                        O0[4*g+2]*inv + b0.z, O0[4*g+3]*inv + b0.w);
        *(float4*)&ot[slot * 68 + co1] =
            make_float4(O1[4*g+0]*inv + b1.x, O1[4*g+1]*inv + b1.y,
                        O1[4*g+2]*inv + b1.z, O1[4*g+3]*inv + b1.w);
      }
    }
    __syncthreads();
    float4* out4 = (float4*)(out + (nrow + ph * 128) * 64);
    #pragma unroll
    for (int i = 0; i < 4; ++i) {
      const int idx = i * 512 + t;           // 0..2047
      const int row = idx >> 4, c4 = idx & 15;
      out4[idx] = *(const float4*)&ot[row * 68 + c4 * 4];
    }
    __syncthreads();
  }
}

// ---------------------------------------------------------------------------
extern "C" void kernel_launch(void* const* d_in, const int* in_sizes, int n_in,
                              void* d_out, int out_size, void* d_ws, size_t ws_size,
                              hipStream_t stream) {
  const float* x   = (const float*)d_in[0];
  const float* Wq  = (const float*)d_in[3];
  const float* Wkv = (const float*)d_in[4];
  const float* Kw  = (const float*)d_in[5];
  const float* sb  = (const float*)d_in[6];
  const float* gam = (const float*)d_in[7];
  const float* bet = (const float*)d_in[8];
  const float* Wp  = (const float*)d_in[9];
  const float* bp  = (const float*)d_in[10];
  float* out = (float*)d_out;

  unsigned short* xrb = (unsigned short*)d_ws;        // 8*131072 = 2 MB
  unsigned short* kbl = xrb + 1048576;                // 256 KB
  unsigned short* vbl = kbl + 131072;                 // 256 KB
  unsigned short* kbt = vbl + 131072;                 // 512 KB
  float* wkp = (float*)(kbt + 262144);                // 16 KB
  float* wvp = wkp + 4096;                            // 16 KB

  prep<<<1056, 256, 0, stream>>>(Wq, Wp, Kw, Wkv, kbt, wkp, wvp);
  conv_mfma<<<1024, 256, 0, stream>>>(x, kbt, xrb);
  ln_kv<<<512, 256, 0, stream>>>(xrb, sb, gam, bet, wkp, wvp, kbl, vbl);
  attn_mfma<<<512, 512, 0, stream>>>(x, kbl, vbl, bp, out);
}